// Round 1
// baseline (179.802 us; speedup 1.0000x reference)
//
#include <hip/hip_runtime.h>

// Problem constants (from reference setup_inputs)
#define L_DIM 12
#define B_DIM 8
#define H_DIM 12
#define S_DIM 384
#define S2    (S_DIM * S_DIM)   // 147456
#define M_DIM 32
#define NL 3
#define NH 4
#define CH 512                   // st elements per chunk
#define NCH (S2 / CH)            // 288 chunks
#define NXCD 8

// ---------------- kernel 1: per-(m,chunk) partial scores ----------------
// grid = NCH*M_DIM blocks, 128 threads. Each thread: one float4 (4 st).
// Block->(m,chunk) mapping puts all 32 m-blocks of a chunk on one XCD
// (assuming round-robin physical blockIdx % 8 -> XCD) so the 1152-plane
// working set (2.36 MB) is reused from that XCD's L2.
__global__ __launch_bounds__(128) void pfe_partial(
    const float* __restrict__ attn,
    const float* __restrict__ refs,
    const int*   __restrict__ lidx,
    const int*   __restrict__ hidx,
    float*       __restrict__ part)   // [M][B][NCH]
{
    const int p    = blockIdx.x;
    const int xcd  = p & (NXCD - 1);
    const int slot = p >> 3;
    const int m    = slot & (M_DIM - 1);
    const int lc   = slot >> 5;              // 0..NCH/8-1
    const int chunk = lc * NXCD + xcd;       // 0..NCH-1
    const int tid  = threadIdx.x;
    const unsigned st = (unsigned)chunk * CH + (unsigned)tid * 4;

    int ls[NL], hs[NH];
#pragma unroll
    for (int i = 0; i < NL; ++i) ls[i] = lidx[m * NL + i];
#pragma unroll
    for (int j = 0; j < NH; ++j) hs[j] = hidx[m * NH + j];

    float4 acc[B_DIM];
#pragma unroll
    for (int b = 0; b < B_DIM; ++b) acc[b] = make_float4(0.f, 0.f, 0.f, 0.f);

#pragma unroll
    for (int i = 0; i < NL; ++i) {
#pragma unroll
        for (int j = 0; j < NH; ++j) {
            // index = ((l*B + b)*H + h)*S2 + st
            unsigned base = (unsigned)(ls[i] * (B_DIM * H_DIM) + hs[j]) * (unsigned)S2 + st;
#pragma unroll
            for (int b = 0; b < B_DIM; ++b) {
                const float4 v = *reinterpret_cast<const float4*>(
                    attn + base + (unsigned)b * (unsigned)(H_DIM * S2));
                acc[b].x += v.x; acc[b].y += v.y; acc[b].z += v.z; acc[b].w += v.w;
            }
        }
    }

    const float c12 = 1.0f / 12.0f;
    float4 pm[B_DIM];
#pragma unroll
    for (int b = 0; b < B_DIM; ++b) {
        pm[b].x = acc[b].x * c12; pm[b].y = acc[b].y * c12;
        pm[b].z = acc[b].z * c12; pm[b].w = acc[b].w * c12;
    }

    // mean over batch
    float4 mu = make_float4(0.f, 0.f, 0.f, 0.f);
#pragma unroll
    for (int b = 0; b < B_DIM; ++b) {
        mu.x += pm[b].x; mu.y += pm[b].y; mu.z += pm[b].z; mu.w += pm[b].w;
    }
    mu.x *= 0.125f; mu.y *= 0.125f; mu.z *= 0.125f; mu.w *= 0.125f;

    // ddof=1 variance
    float4 ss = make_float4(0.f, 0.f, 0.f, 0.f);
#pragma unroll
    for (int b = 0; b < B_DIM; ++b) {
        float dx = pm[b].x - mu.x, dy = pm[b].y - mu.y,
              dz = pm[b].z - mu.z, dw = pm[b].w - mu.w;
        ss.x += dx * dx; ss.y += dy * dy; ss.z += dz * dz; ss.w += dw * dw;
    }
    const float c7 = 1.0f / 7.0f;
    float4 inv;
    inv.x = 1.0f / fmaxf(sqrtf(ss.x * c7), 1e-8f);
    inv.y = 1.0f / fmaxf(sqrtf(ss.y * c7), 1e-8f);
    inv.z = 1.0f / fmaxf(sqrtf(ss.z * c7), 1e-8f);
    inv.w = 1.0f / fmaxf(sqrtf(ss.w * c7), 1e-8f);

    const float4 r = *reinterpret_cast<const float4*>(refs + (unsigned)m * (unsigned)S2 + st);

    float s[B_DIM];
#pragma unroll
    for (int b = 0; b < B_DIM; ++b) {
        float zx = (pm[b].x - r.x) * inv.x;
        float zy = (pm[b].y - r.y) * inv.y;
        float zz = (pm[b].z - r.z) * inv.z;
        float zw = (pm[b].w - r.w) * inv.w;
        s[b] = zx * zx + zy * zy + zz * zz + zw * zw;
    }

    // reduce across 128 threads (2 waves)
#pragma unroll
    for (int b = 0; b < B_DIM; ++b) {
        float v = s[b];
#pragma unroll
        for (int off = 32; off > 0; off >>= 1) v += __shfl_down(v, off);
        s[b] = v;
    }
    __shared__ float lds[2 * B_DIM];
    const int lane = tid & 63, wave = tid >> 6;
    if (lane == 0) {
#pragma unroll
        for (int b = 0; b < B_DIM; ++b) lds[wave * B_DIM + b] = s[b];
    }
    __syncthreads();
    if (tid < B_DIM) {
        float tot = lds[tid] + lds[B_DIM + tid];
        part[(m * B_DIM + tid) * NCH + chunk] = tot;
    }
}

// ---------------- kernel 2: fixed-order final reduction ----------------
__global__ __launch_bounds__(256) void pfe_final(
    const float* __restrict__ part, float* __restrict__ out)
{
    const int t = threadIdx.x;
    if (t >= M_DIM * B_DIM) return;
    const int m = t & (M_DIM - 1);
    const int b = t >> 5;
    const float* p = part + (m * B_DIM + b) * NCH;
    float sum = 0.f;
    for (int c = 0; c < NCH; ++c) sum += p[c];
    out[b * M_DIM + m] = sum * (1.0f / (float)S2);
}

// ---------------- fallback path (tiny ws): atomics into out ----------------
__global__ void pfe_zero(float* __restrict__ out) {
    if (threadIdx.x < M_DIM * B_DIM) out[threadIdx.x] = 0.f;
}

__global__ __launch_bounds__(128) void pfe_partial_atomic(
    const float* __restrict__ attn,
    const float* __restrict__ refs,
    const int*   __restrict__ lidx,
    const int*   __restrict__ hidx,
    float*       __restrict__ out)
{
    const int p    = blockIdx.x;
    const int xcd  = p & (NXCD - 1);
    const int slot = p >> 3;
    const int m    = slot & (M_DIM - 1);
    const int lc   = slot >> 5;
    const int chunk = lc * NXCD + xcd;
    const int tid  = threadIdx.x;
    const unsigned st = (unsigned)chunk * CH + (unsigned)tid * 4;

    int ls[NL], hs[NH];
#pragma unroll
    for (int i = 0; i < NL; ++i) ls[i] = lidx[m * NL + i];
#pragma unroll
    for (int j = 0; j < NH; ++j) hs[j] = hidx[m * NH + j];

    float4 acc[B_DIM];
#pragma unroll
    for (int b = 0; b < B_DIM; ++b) acc[b] = make_float4(0.f, 0.f, 0.f, 0.f);
#pragma unroll
    for (int i = 0; i < NL; ++i)
#pragma unroll
        for (int j = 0; j < NH; ++j) {
            unsigned base = (unsigned)(ls[i] * (B_DIM * H_DIM) + hs[j]) * (unsigned)S2 + st;
#pragma unroll
            for (int b = 0; b < B_DIM; ++b) {
                const float4 v = *reinterpret_cast<const float4*>(
                    attn + base + (unsigned)b * (unsigned)(H_DIM * S2));
                acc[b].x += v.x; acc[b].y += v.y; acc[b].z += v.z; acc[b].w += v.w;
            }
        }
    const float c12 = 1.0f / 12.0f;
    float4 pm[B_DIM];
#pragma unroll
    for (int b = 0; b < B_DIM; ++b) {
        pm[b].x = acc[b].x * c12; pm[b].y = acc[b].y * c12;
        pm[b].z = acc[b].z * c12; pm[b].w = acc[b].w * c12;
    }
    float4 mu = make_float4(0.f, 0.f, 0.f, 0.f);
#pragma unroll
    for (int b = 0; b < B_DIM; ++b) {
        mu.x += pm[b].x; mu.y += pm[b].y; mu.z += pm[b].z; mu.w += pm[b].w;
    }
    mu.x *= 0.125f; mu.y *= 0.125f; mu.z *= 0.125f; mu.w *= 0.125f;
    float4 ss = make_float4(0.f, 0.f, 0.f, 0.f);
#pragma unroll
    for (int b = 0; b < B_DIM; ++b) {
        float dx = pm[b].x - mu.x, dy = pm[b].y - mu.y,
              dz = pm[b].z - mu.z, dw = pm[b].w - mu.w;
        ss.x += dx * dx; ss.y += dy * dy; ss.z += dz * dz; ss.w += dw * dw;
    }
    const float c7 = 1.0f / 7.0f;
    float4 inv;
    inv.x = 1.0f / fmaxf(sqrtf(ss.x * c7), 1e-8f);
    inv.y = 1.0f / fmaxf(sqrtf(ss.y * c7), 1e-8f);
    inv.z = 1.0f / fmaxf(sqrtf(ss.z * c7), 1e-8f);
    inv.w = 1.0f / fmaxf(sqrtf(ss.w * c7), 1e-8f);
    const float4 r = *reinterpret_cast<const float4*>(refs + (unsigned)m * (unsigned)S2 + st);
    float s[B_DIM];
#pragma unroll
    for (int b = 0; b < B_DIM; ++b) {
        float zx = (pm[b].x - r.x) * inv.x;
        float zy = (pm[b].y - r.y) * inv.y;
        float zz = (pm[b].z - r.z) * inv.z;
        float zw = (pm[b].w - r.w) * inv.w;
        s[b] = zx * zx + zy * zy + zz * zz + zw * zw;
    }
#pragma unroll
    for (int b = 0; b < B_DIM; ++b) {
        float v = s[b];
#pragma unroll
        for (int off = 32; off > 0; off >>= 1) v += __shfl_down(v, off);
        s[b] = v;
    }
    __shared__ float lds[2 * B_DIM];
    const int lane = tid & 63, wave = tid >> 6;
    if (lane == 0) {
#pragma unroll
        for (int b = 0; b < B_DIM; ++b) lds[wave * B_DIM + b] = s[b];
    }
    __syncthreads();
    if (tid < B_DIM) {
        float tot = (lds[tid] + lds[B_DIM + tid]) * (1.0f / (float)S2);
        atomicAdd(&out[tid * M_DIM + m], tot);
    }
}

extern "C" void kernel_launch(void* const* d_in, const int* in_sizes, int n_in,
                              void* d_out, int out_size, void* d_ws, size_t ws_size,
                              hipStream_t stream) {
    const float* attn = (const float*)d_in[0];
    const float* refs = (const float*)d_in[1];
    const int*   lidx = (const int*)d_in[2];
    const int*   hidx = (const int*)d_in[3];
    float* out = (float*)d_out;

    const int nblocks = NCH * M_DIM;  // 9216
    const size_t ws_needed = (size_t)M_DIM * B_DIM * NCH * sizeof(float);

    if (ws_size >= ws_needed) {
        float* part = (float*)d_ws;
        pfe_partial<<<nblocks, 128, 0, stream>>>(attn, refs, lidx, hidx, part);
        pfe_final<<<1, 256, 0, stream>>>(part, out);
    } else {
        pfe_zero<<<1, 256, 0, stream>>>(out);
        pfe_partial_atomic<<<nblocks, 128, 0, stream>>>(attn, refs, lidx, hidx, out);
    }
}

// Round 2
// 178.417 us; speedup vs baseline: 1.0078x; 1.0078x over previous
//
#include <hip/hip_runtime.h>

// Problem constants (from reference setup_inputs)
#define L_DIM 12
#define B_DIM 8
#define H_DIM 12
#define S_DIM 384
#define S2    (S_DIM * S_DIM)   // 147456
#define M_DIM 32
#define NL 3
#define NH 4
#define CH 512                   // st elements per chunk (128 thr * float4)
#define NCH (S2 / CH)            // 288 chunks
#define NXCD 8

// One block per (m, chunk). 128 threads, each owns one float4 of st.
// Key ideas vs v1:
//  - all m-blocks iterate planes in CANONICAL (l*16+h) sorted order, so the
//    ~3 m's sharing a plane touch it within a few plane-steps -> L2 line is
//    still hot (v1 iterated private order; 10 chunks x 2MB in flight thrashed
//    the 4MB/XCD L2).
//  - duplicate (l,h) pairs are merged with integer weights (reference's .add
//    semantics), cutting plane loads 12 -> ~9.7 avg per m.
//  - XCD swizzle: blockIdx%8 selects chunk's XCD so all 32 m-blocks of a
//    chunk share one L2.
template <bool ATOMIC>
__global__ __launch_bounds__(128) void pfe_main(
    const float* __restrict__ attn,
    const float* __restrict__ refs,
    const int*   __restrict__ lidx,
    const int*   __restrict__ hidx,
    float*       __restrict__ outp)   // ATOMIC ? out[B][M] : part[M][B][NCH]
{
    const int p    = blockIdx.x;
    const int xcd  = p & (NXCD - 1);
    const int slot = p >> 3;
    const int m    = slot & (M_DIM - 1);
    const int lc   = slot >> 5;              // 0..NCH/8-1
    const int chunk = lc * NXCD + xcd;       // 0..NCH-1
    const int tid  = threadIdx.x;
    const unsigned st = (unsigned)chunk * CH + (unsigned)tid * 4;

    __shared__ int   s_mk[NL * NH];
    __shared__ float s_mw[NL * NH];
    __shared__ int   s_nm;
    __shared__ float s_red[2 * B_DIM];

    if (tid == 0) {
        int keys[NL * NH];
#pragma unroll
        for (int i = 0; i < NL; ++i) {
            const int l = lidx[m * NL + i];
#pragma unroll
            for (int j = 0; j < NH; ++j)
                keys[i * NH + j] = l * 16 + hidx[m * NH + j];
        }
        // insertion sort (12 elems, single thread, values identical per block)
        for (int i = 1; i < NL * NH; ++i) {
            const int k = keys[i];
            int j = i - 1;
            for (; j >= 0 && keys[j] > k; --j) keys[j + 1] = keys[j];
            keys[j + 1] = k;
        }
        // merge duplicates with counts
        int nm = 0;
        for (int i = 0; i < NL * NH; ++i) {
            if (nm > 0 && s_mk[nm - 1] == keys[i]) {
                s_mw[nm - 1] += 1.0f;
            } else {
                s_mk[nm] = keys[i];
                s_mw[nm] = 1.0f;
                ++nm;
            }
        }
        s_nm = nm;
    }
    __syncthreads();

    // reference chunk (independent, issue early)
    const float4 r = *reinterpret_cast<const float4*>(refs + (unsigned)m * (unsigned)S2 + st);

    float4 acc[B_DIM];
#pragma unroll
    for (int b = 0; b < B_DIM; ++b) acc[b] = make_float4(0.f, 0.f, 0.f, 0.f);

    const int nm = s_nm;
    for (int e = 0; e < nm; ++e) {
        const int   k = s_mk[e];
        const float w = s_mw[e];
        const int l = k >> 4, h = k & 15;
        const unsigned base = (unsigned)(l * (B_DIM * H_DIM) + h) * (unsigned)S2 + st;
#pragma unroll
        for (int b = 0; b < B_DIM; ++b) {
            const float4 v = *reinterpret_cast<const float4*>(
                attn + base + (unsigned)b * (unsigned)(H_DIM * S2));
            acc[b].x = fmaf(w, v.x, acc[b].x);
            acc[b].y = fmaf(w, v.y, acc[b].y);
            acc[b].z = fmaf(w, v.z, acc[b].z);
            acc[b].w = fmaf(w, v.w, acc[b].w);
        }
    }

    const float c12 = 1.0f / 12.0f;
    float4 pm[B_DIM];
#pragma unroll
    for (int b = 0; b < B_DIM; ++b) {
        pm[b].x = acc[b].x * c12; pm[b].y = acc[b].y * c12;
        pm[b].z = acc[b].z * c12; pm[b].w = acc[b].w * c12;
    }

    // mean over batch
    float4 mu = make_float4(0.f, 0.f, 0.f, 0.f);
#pragma unroll
    for (int b = 0; b < B_DIM; ++b) {
        mu.x += pm[b].x; mu.y += pm[b].y; mu.z += pm[b].z; mu.w += pm[b].w;
    }
    mu.x *= 0.125f; mu.y *= 0.125f; mu.z *= 0.125f; mu.w *= 0.125f;

    // ddof=1 variance -> 1/std (clamped)
    float4 ss = make_float4(0.f, 0.f, 0.f, 0.f);
#pragma unroll
    for (int b = 0; b < B_DIM; ++b) {
        const float dx = pm[b].x - mu.x, dy = pm[b].y - mu.y,
                    dz = pm[b].z - mu.z, dw = pm[b].w - mu.w;
        ss.x += dx * dx; ss.y += dy * dy; ss.z += dz * dz; ss.w += dw * dw;
    }
    const float c7 = 1.0f / 7.0f;
    float4 inv;
    inv.x = 1.0f / fmaxf(sqrtf(ss.x * c7), 1e-8f);
    inv.y = 1.0f / fmaxf(sqrtf(ss.y * c7), 1e-8f);
    inv.z = 1.0f / fmaxf(sqrtf(ss.z * c7), 1e-8f);
    inv.w = 1.0f / fmaxf(sqrtf(ss.w * c7), 1e-8f);

    float s[B_DIM];
#pragma unroll
    for (int b = 0; b < B_DIM; ++b) {
        const float zx = (pm[b].x - r.x) * inv.x;
        const float zy = (pm[b].y - r.y) * inv.y;
        const float zz = (pm[b].z - r.z) * inv.z;
        const float zw = (pm[b].w - r.w) * inv.w;
        s[b] = zx * zx + zy * zy + zz * zz + zw * zw;
    }

    // reduce across 128 threads (2 waves of 64)
#pragma unroll
    for (int b = 0; b < B_DIM; ++b) {
        float v = s[b];
#pragma unroll
        for (int off = 32; off > 0; off >>= 1) v += __shfl_down(v, off);
        s[b] = v;
    }
    const int lane = tid & 63, wave = tid >> 6;
    if (lane == 0) {
#pragma unroll
        for (int b = 0; b < B_DIM; ++b) s_red[wave * B_DIM + b] = s[b];
    }
    __syncthreads();
    if (tid < B_DIM) {
        const float tot = s_red[tid] + s_red[B_DIM + tid];
        if (ATOMIC) {
            atomicAdd(&outp[tid * M_DIM + m], tot * (1.0f / (float)S2));
        } else {
            outp[(m * B_DIM + tid) * NCH + chunk] = tot;
        }
    }
}

// ---------------- kernel 2: fixed-order final reduction ----------------
__global__ __launch_bounds__(256) void pfe_final(
    const float* __restrict__ part, float* __restrict__ out)
{
    const int t = threadIdx.x;
    if (t >= M_DIM * B_DIM) return;
    const int m = t & (M_DIM - 1);
    const int b = t >> 5;
    const float* p = part + (m * B_DIM + b) * NCH;
    float sum = 0.f;
    for (int c = 0; c < NCH; ++c) sum += p[c];
    out[b * M_DIM + m] = sum * (1.0f / (float)S2);
}

__global__ void pfe_zero(float* __restrict__ out) {
    if (threadIdx.x < M_DIM * B_DIM) out[threadIdx.x] = 0.f;
}

extern "C" void kernel_launch(void* const* d_in, const int* in_sizes, int n_in,
                              void* d_out, int out_size, void* d_ws, size_t ws_size,
                              hipStream_t stream) {
    const float* attn = (const float*)d_in[0];
    const float* refs = (const float*)d_in[1];
    const int*   lidx = (const int*)d_in[2];
    const int*   hidx = (const int*)d_in[3];
    float* out = (float*)d_out;

    const int nblocks = NCH * M_DIM;  // 9216
    const size_t ws_needed = (size_t)M_DIM * B_DIM * NCH * sizeof(float);

    if (ws_size >= ws_needed) {
        float* part = (float*)d_ws;
        pfe_main<false><<<nblocks, 128, 0, stream>>>(attn, refs, lidx, hidx, part);
        pfe_final<<<1, 256, 0, stream>>>(part, out);
    } else {
        pfe_zero<<<1, 256, 0, stream>>>(out);
        pfe_main<true><<<nblocks, 128, 0, stream>>>(attn, refs, lidx, hidx, out);
    }
}